// Round 1
// baseline (143.004 us; speedup 1.0000x reference)
//
#include <hip/hip_runtime.h>
#include <hip/hip_bf16.h>

typedef __attribute__((ext_vector_type(8))) short bf16x8;
typedef __attribute__((ext_vector_type(4))) float f32x4;
typedef __hip_bfloat16 bf16;

#define NROWS 8192
#define DIN   2048
#define DD    768
#define CCLS  100
#define BTROWS 896   // 768 P rows + 100 muP rows + 28 zero pad

// ---------------- prep kernels ----------------

// x f32 -> bf16, 4 elems/thread
__global__ void k_convert_x(const float* __restrict__ x, bf16* __restrict__ xb) {
  long i = ((long)blockIdx.x * 256 + threadIdx.x) * 4;
  float4 v = *(const float4*)(x + i);
  union { bf16 h[4]; uint2 u; } t;
  t.h[0] = __float2bfloat16(v.x);
  t.h[1] = __float2bfloat16(v.y);
  t.h[2] = __float2bfloat16(v.z);
  t.h[3] = __float2bfloat16(v.w);
  *(uint2*)(xb + i) = t.u;
}

// W [2048,768] f32 -> Wt [768,2048] bf16 (tiled transpose)
__global__ void k_transpose_W(const float* __restrict__ W, bf16* __restrict__ Wt) {
  __shared__ float tile[32][33];
  int tx = threadIdx.x & 31;
  int ty = threadIdx.x >> 5;          // 0..7
  int n0 = blockIdx.x * 32;           // col tile in W (row tile in Wt)
  int k0 = blockIdx.y * 32;           // row tile in W
#pragma unroll
  for (int i = 0; i < 4; ++i)
    tile[ty + 8*i][tx] = W[(long)(k0 + ty + 8*i) * DD + n0 + tx];
  __syncthreads();
#pragma unroll
  for (int i = 0; i < 4; ++i)
    Wt[(long)(n0 + ty + 8*i) * DIN + k0 + tx] = __float2bfloat16(tile[tx][ty + 8*i]);
}

// P f32 -> BT rows [0,768) (P symmetric: no transpose needed); zero pad rows [868,896);
// init halfmPm pad entries [100,128) to +1e30 (forces score -inf on pad cols)
__global__ void k_convert_P(const float* __restrict__ P, bf16* __restrict__ BT,
                            float* __restrict__ halfmPm) {
  int id = blockIdx.x * 256 + threadIdx.x;     // 0 .. 896*768-1
  int r = id / DD;
  if (r < DD)                BT[id] = __float2bfloat16(P[id]);
  else if (r >= DD + CCLS)   BT[id] = __float2bfloat16(0.f);
  if (id >= CCLS && id < 128) halfmPm[id] = 1e30f;
}

// per class c: muP[c][:] = mu[c] @ P  -> BT row 768+c (bf16); halfmPm[c] = 0.5*mu[c]P mu[c]^T
__global__ __launch_bounds__(256) void k_prep_mu(const float* __restrict__ mu,
                                                 const float* __restrict__ P,
                                                 bf16* __restrict__ BT,
                                                 float* __restrict__ halfmPm) {
  __shared__ float muL[DD];
  __shared__ float red[256];
  const int tid = threadIdx.x;
  const int c = blockIdx.x;
  for (int i = tid; i < DD; i += 256) muL[i] = mu[(long)c * DD + i];
  __syncthreads();
  float a0 = 0.f, a1 = 0.f, a2 = 0.f;
  for (int d = 0; d < DD; ++d) {
    float md = muL[d];
    const float* Pr = P + (long)d * DD;
    a0 += md * Pr[tid];
    a1 += md * Pr[tid + 256];
    a2 += md * Pr[tid + 512];
  }
  long rb = (long)(DD + c) * DD;
  BT[rb + tid]       = __float2bfloat16(a0);
  BT[rb + tid + 256] = __float2bfloat16(a1);
  BT[rb + tid + 512] = __float2bfloat16(a2);
  red[tid] = a0 * muL[tid] + a1 * muL[tid + 256] + a2 * muL[tid + 512];
  __syncthreads();
  for (int s = 128; s > 0; s >>= 1) {
    if (tid < s) red[tid] += red[tid + s];
    __syncthreads();
  }
  if (tid == 0) halfmPm[c] = 0.5f * red[0];
}

// ---------------- GEMM core (m97 structure: 128x128 tile, BK=64, 4 waves) ----------------
// A [M,K] row-major bf16, B^T [N,K] row-major bf16; both staged via global_load_lds width 16.

template<int LDK>
__device__ __forceinline__ void gemm_tile_mainloop(
    const bf16* __restrict__ A, const bf16* __restrict__ B,
    long rowA0, long rowB0, bf16* As, bf16* Bs, f32x4 acc[4][4])
{
  const int tid  = threadIdx.x;
  const int lane = tid & 63;
  const int w    = tid >> 6;
  const int wr = w >> 1, wc = w & 1;
  const int fr = lane & 15, fq = lane >> 4;
  const int sr = lane >> 3;            // staging: row within wave-chunk
  const int sc = (lane & 7) * 8;       // staging: k offset (8 bf16 = 16B)

  for (int kt = 0; kt < LDK; kt += 64) {
#pragma unroll
    for (int i = 0; i < 4; ++i) {
      const int rr = i * 32 + w * 8;   // wave-uniform row base of this 1KB chunk
      const bf16* gA = A + (rowA0 + rr + sr) * (long)LDK + kt + sc;
      const bf16* gB = B + (rowB0 + rr + sr) * (long)LDK + kt + sc;
      __builtin_amdgcn_global_load_lds(
          (const __attribute__((address_space(1))) unsigned int*)gA,
          (__attribute__((address_space(3))) unsigned int*)(As + rr * 64), 16, 0, 0);
      __builtin_amdgcn_global_load_lds(
          (const __attribute__((address_space(1))) unsigned int*)gB,
          (__attribute__((address_space(3))) unsigned int*)(Bs + rr * 64), 16, 0, 0);
    }
    __syncthreads();   // compiler drains vmcnt before s_barrier
#pragma unroll
    for (int kk = 0; kk < 64; kk += 32) {
      bf16x8 av[4], bv[4];
#pragma unroll
      for (int m = 0; m < 4; ++m)
        av[m] = *(const bf16x8*)(As + (wr * 64 + m * 16 + fr) * 64 + kk + fq * 8);
#pragma unroll
      for (int n = 0; n < 4; ++n)
        bv[n] = *(const bf16x8*)(Bs + (wc * 64 + n * 16 + fr) * 64 + kk + fq * 8);
#pragma unroll
      for (int m = 0; m < 4; ++m)
#pragma unroll
        for (int n = 0; n < 4; ++n)
          acc[m][n] = __builtin_amdgcn_mfma_f32_16x16x32_bf16(av[m], bv[n], acc[m][n], 0, 0, 0);
    }
    __syncthreads();
  }
}

// GEMM1: zb = xb @ Wt^T   [8192,2048]x[768,2048]^T -> bf16 [8192,768]
__global__ __launch_bounds__(256) void k_gemm1(const bf16* __restrict__ xb,
                                               const bf16* __restrict__ Wt,
                                               bf16* __restrict__ zb) {
  __shared__ __align__(16) bf16 As[128 * 64];
  __shared__ __align__(16) bf16 Bs[128 * 64];
  f32x4 acc[4][4];
#pragma unroll
  for (int m = 0; m < 4; ++m)
#pragma unroll
    for (int n = 0; n < 4; ++n) acc[m][n] = (f32x4){0.f, 0.f, 0.f, 0.f};
  const long bm = blockIdx.y, bn = blockIdx.x;
  gemm_tile_mainloop<DIN>(xb, Wt, bm * 128, bn * 128, As, Bs, acc);
  const int tid = threadIdx.x, lane = tid & 63, w = tid >> 6;
  const int wr = w >> 1, wc = w & 1, fr = lane & 15, fq = lane >> 4;
#pragma unroll
  for (int m = 0; m < 4; ++m)
#pragma unroll
    for (int n = 0; n < 4; ++n)
#pragma unroll
      for (int j = 0; j < 4; ++j) {
        long row = bm * 128 + wr * 64 + m * 16 + fq * 4 + j;
        long col = bn * 128 + wc * 64 + n * 16 + fr;
        zb[row * DD + col] = __float2bfloat16(acc[m][n][j]);
      }
}

// GEMM2: out2 = zb @ BT^T, BT = [P | muP | 0] as [896,768].
// bn<6: zP tile -> rowdot with zb -> atomicAdd zPz[row]
// bn==6: score tile -> max_c(s - halfmPm[c]) -> smax[row]
__global__ __launch_bounds__(256) void k_gemm2(const bf16* __restrict__ zb,
                                               const bf16* __restrict__ BT,
                                               const float* __restrict__ halfmPm,
                                               float* __restrict__ zPz,
                                               float* __restrict__ smax) {
  __shared__ __align__(16) bf16 As[128 * 64];
  __shared__ __align__(16) bf16 Bs[128 * 64];
  __shared__ float sred[2][128];
  f32x4 acc[4][4];
#pragma unroll
  for (int m = 0; m < 4; ++m)
#pragma unroll
    for (int n = 0; n < 4; ++n) acc[m][n] = (f32x4){0.f, 0.f, 0.f, 0.f};
  const long bm = blockIdx.y, bn = blockIdx.x;
  gemm_tile_mainloop<DD>(zb, BT, bm * 128, bn * 128, As, Bs, acc);
  const int tid = threadIdx.x, lane = tid & 63, w = tid >> 6;
  const int wr = w >> 1, wc = w & 1, fr = lane & 15, fq = lane >> 4;

  if (bn < 6) {
    float p[4][4];
#pragma unroll
    for (int m = 0; m < 4; ++m)
#pragma unroll
      for (int j = 0; j < 4; ++j) p[m][j] = 0.f;
#pragma unroll
    for (int m = 0; m < 4; ++m)
#pragma unroll
      for (int n = 0; n < 4; ++n)
#pragma unroll
        for (int j = 0; j < 4; ++j) {
          long row = bm * 128 + wr * 64 + m * 16 + fq * 4 + j;
          long col = bn * 128 + wc * 64 + n * 16 + fr;
          p[m][j] += acc[m][n][j] * __bfloat162float(zb[row * DD + col]);
        }
#pragma unroll
    for (int m = 0; m < 4; ++m)
#pragma unroll
      for (int j = 0; j < 4; ++j) {
        float v = p[m][j];
        v += __shfl_xor(v, 1, 64);
        v += __shfl_xor(v, 2, 64);
        v += __shfl_xor(v, 4, 64);
        v += __shfl_xor(v, 8, 64);
        if (fr == 0)
          atomicAdd(&zPz[bm * 128 + wr * 64 + m * 16 + fq * 4 + j], v);
      }
  } else {
    float hm[4];
#pragma unroll
    for (int n = 0; n < 4; ++n) hm[n] = halfmPm[wc * 64 + n * 16 + fr];
    float mx[4][4];
#pragma unroll
    for (int m = 0; m < 4; ++m)
#pragma unroll
      for (int j = 0; j < 4; ++j) mx[m][j] = -3e38f;
#pragma unroll
    for (int m = 0; m < 4; ++m)
#pragma unroll
      for (int n = 0; n < 4; ++n)
#pragma unroll
        for (int j = 0; j < 4; ++j)
          mx[m][j] = fmaxf(mx[m][j], acc[m][n][j] - hm[n]);
#pragma unroll
    for (int m = 0; m < 4; ++m)
#pragma unroll
      for (int j = 0; j < 4; ++j) {
        float v = mx[m][j];
        v = fmaxf(v, __shfl_xor(v, 1, 64));
        v = fmaxf(v, __shfl_xor(v, 2, 64));
        v = fmaxf(v, __shfl_xor(v, 4, 64));
        v = fmaxf(v, __shfl_xor(v, 8, 64));
        if (fr == 0) sred[wc][wr * 64 + m * 16 + fq * 4 + j] = v;
      }
    __syncthreads();
    if (tid < 128) smax[bm * 128 + tid] = fmaxf(sred[0][tid], sred[1][tid]);
  }
}

__global__ void k_final(const float* __restrict__ smax, const float* __restrict__ zPz,
                        float* __restrict__ out) {
  int i = blockIdx.x * 256 + threadIdx.x;
  if (i < NROWS) out[i] = smax[i] - 0.5f * zPz[i];
}

// ---------------- launch ----------------

extern "C" void kernel_launch(void* const* d_in, const int* in_sizes, int n_in,
                              void* d_out, int out_size, void* d_ws, size_t ws_size,
                              hipStream_t stream) {
  const float* x  = (const float*)d_in[0];
  const float* W  = (const float*)d_in[1];
  const float* mu = (const float*)d_in[2];
  const float* P  = (const float*)d_in[3];
  float* out = (float*)d_out;

  char* ws = (char*)d_ws;
  // ws layout (bytes, all 256-aligned)
  bf16*  xb   = (bf16*)(ws);                       // 8192*2048*2 = 33,554,432
  bf16*  Wt   = (bf16*)(ws + 33554432);            // 768*2048*2  =  3,145,728
  bf16*  BT   = (bf16*)(ws + 36700160);            // 896*768*2   =  1,376,256
  bf16*  zb   = (bf16*)(ws + 38076416);            // 8192*768*2  = 12,582,912
  float* hm   = (float*)(ws + 50659328);           // 128*4
  float* zPz  = (float*)(ws + 50659840);           // 8192*4
  float* smax = (float*)(ws + 50692608);           // 8192*4  (end ~50.7 MB)

  hipMemsetAsync(zPz, 0, NROWS * sizeof(float), stream);
  k_convert_x  <<<16384, 256, 0, stream>>>(x, xb);
  k_transpose_W<<<dim3(24, 64), 256, 0, stream>>>(W, Wt);
  k_convert_P  <<<2688, 256, 0, stream>>>(P, BT, hm);
  k_prep_mu    <<<CCLS, 256, 0, stream>>>(mu, P, BT, hm);
  k_gemm1      <<<dim3(6, 64), 256, 0, stream>>>(xb, Wt, zb);
  k_gemm2      <<<dim3(7, 64), 256, 0, stream>>>(zb, BT, hm, zPz, smax);
  k_final      <<<32, 256, 0, stream>>>(smax, zPz, out);
}